// Round 5
// baseline (237.132 us; speedup 1.0000x reference)
//
#include <hip/hip_runtime.h>

#define BN 32768
#define NB 16
#define NN 2048
#define CC 256
#define JT 64
#define NTILES (NN / JT)

using short8  = __attribute__((ext_vector_type(8))) short;
using floatx4 = __attribute__((ext_vector_type(4))) float;

__device__ __forceinline__ unsigned short f2bf(float f) {
  unsigned u = __builtin_bit_cast(unsigned, f);
  u += 0x7fffu + ((u >> 16) & 1u);
  return (unsigned short)(u >> 16);
}
__device__ __forceinline__ float bf2f(unsigned short h) {
  unsigned u = ((unsigned)h) << 16;
  return __builtin_bit_cast(float, u);
}
__device__ __forceinline__ unsigned char f2fp8(float f) {
  return (unsigned char)(__builtin_amdgcn_cvt_pk_fp8_f32(f, f, 0, false) & 0xff);
}
__device__ __forceinline__ long lo64(uint4 v) {
  uint2 t; t.x = v.x; t.y = v.y; return __builtin_bit_cast(long, t);
}
__device__ __forceinline__ long hi64(uint4 v) {
  uint2 t; t.x = v.z; t.y = v.w; return __builtin_bit_cast(long, t);
}

// ---------------- LayerNorm: one wave per row, bf16 output ----------------
__global__ __launch_bounds__(256) void ln_kernel(
    const float* __restrict__ x, const float* __restrict__ lw,
    const float* __restrict__ lb, unsigned short* __restrict__ normed) {
  int row  = blockIdx.x * 4 + (threadIdx.x >> 6);
  int lane = threadIdx.x & 63;
  float4 v = ((const float4*)(x + (size_t)row * CC))[lane];
  float s  = v.x + v.y + v.z + v.w;
  float s2 = v.x * v.x + v.y * v.y + v.z * v.z + v.w * v.w;
#pragma unroll
  for (int off = 32; off; off >>= 1) {
    s  += __shfl_xor(s, off);
    s2 += __shfl_xor(s2, off);
  }
  float mu = s * (1.0f / CC);
  float rs = rsqrtf(s2 * (1.0f / CC) - mu * mu + 1e-5f);
  float4 w = ((const float4*)lw)[lane];
  float4 b = ((const float4*)lb)[lane];
  ushort4 o;
  o.x = f2bf((v.x - mu) * rs * w.x + b.x);
  o.y = f2bf((v.y - mu) * rs * w.y + b.y);
  o.z = f2bf((v.z - mu) * rs * w.z + b.z);
  o.w = f2bf((v.w - mu) * rs * w.w + b.w);
  ((ushort4*)(normed + (size_t)row * CC))[lane] = o;
}

// ------------- transpose fp32 KxN weight -> bf16 NxK (row-major) -------------
__global__ void wconv_kernel(const float* __restrict__ src,
                             unsigned short* __restrict__ dst, int K, int N) {
  int idx = blockIdx.x * 256 + threadIdx.x;
  if (idx >= K * N) return;
  int n = idx / K, k = idx - n * K;
  dst[idx] = f2bf(src[(size_t)k * N + n]);
}

// --------- GEMM1: normed @ w_hidden + b, silu; v -> blocked fp8 VB, gate bf16 ---------
__global__ __launch_bounds__(256) void gemm_hidden(
    const unsigned short* __restrict__ A, const unsigned short* __restrict__ BT,
    const float* __restrict__ bias,
    unsigned char* __restrict__ vB, unsigned short* __restrict__ gout) {
  int wave = threadIdx.x >> 6, lane = threadIdx.x & 63;
  int m = lane & 15, g4 = lane >> 4, kb = g4 * 8;
  int m0 = blockIdx.x * 128 + (wave & 1) * 64;
  int n0 = blockIdx.y * 128 + (wave >> 1) * 64;
  floatx4 acc[4][4] = {};
#pragma unroll
  for (int ks = 0; ks < 8; ++ks) {
    short8 af[4], bf[4];
#pragma unroll
    for (int i = 0; i < 4; ++i)
      af[i] = *(const short8*)(A + (size_t)(m0 + i * 16 + m) * CC + ks * 32 + kb);
#pragma unroll
    for (int j = 0; j < 4; ++j)
      bf[j] = *(const short8*)(BT + (size_t)(n0 + j * 16 + m) * CC + ks * 32 + kb);
#pragma unroll
    for (int i = 0; i < 4; ++i)
#pragma unroll
      for (int j = 0; j < 4; ++j)
        acc[i][j] = __builtin_amdgcn_mfma_f32_16x16x32_bf16(af[i], bf[j], acc[i][j], 0, 0, 0);
  }
#pragma unroll
  for (int j = 0; j < 4; ++j) {
    int col = n0 + j * 16 + m;
    float bv = bias[col];
#pragma unroll
    for (int i = 0; i < 4; ++i)
#pragma unroll
      for (int r = 0; r < 4; ++r) {
        int row = m0 + i * 16 + g4 * 4 + r;
        float h = acc[i][j][r] + bv;
        float sv = h / (1.0f + __expf(-h));
        if (col < CC) {
          int bb = row >> 11, n = row & 2047;
          size_t addr = ((size_t)(bb * 32 + (n >> 6)) * 256 + col) * 64
                      + ((n >> 3) & 3) * 16 + ((n >> 5) & 1) * 8 + (n & 7);
          vB[addr] = f2fp8(sv);
        } else {
          gout[(size_t)row * CC + col - CC] = f2bf(sv);
        }
      }
  }
}

// ----------- GEMM2: normed @ w_kv -> Z; q,k fp8 in blocked fragment layout -----------
// layout: [b][j>>4][p=c>>6] 1024B block: (j&15)*64 + ((c>>3)&3)*16 + ((c>>5)&1)*8 + (c&7)
__global__ __launch_bounds__(256) void gemm_kv(
    const unsigned short* __restrict__ A, const unsigned short* __restrict__ BT,
    const float* __restrict__ gamma, const float* __restrict__ beta,
    unsigned char* __restrict__ qout, unsigned char* __restrict__ kout) {
  int wave = threadIdx.x >> 6, lane = threadIdx.x & 63;
  int m = lane & 15, g4 = lane >> 4, kb = g4 * 8;
  int m0 = blockIdx.x * 128 + (wave & 1) * 64;
  int n0 = blockIdx.y * 128 + (wave >> 1) * 64;
  floatx4 acc[4][4] = {};
#pragma unroll
  for (int ks = 0; ks < 8; ++ks) {
    short8 af[4], bf[4];
#pragma unroll
    for (int i = 0; i < 4; ++i)
      af[i] = *(const short8*)(A + (size_t)(m0 + i * 16 + m) * CC + ks * 32 + kb);
#pragma unroll
    for (int j = 0; j < 4; ++j)
      bf[j] = *(const short8*)(BT + (size_t)(n0 + j * 16 + m) * CC + ks * 32 + kb);
#pragma unroll
    for (int i = 0; i < 4; ++i)
#pragma unroll
      for (int j = 0; j < 4; ++j)
        acc[i][j] = __builtin_amdgcn_mfma_f32_16x16x32_bf16(af[i], bf[j], acc[i][j], 0, 0, 0);
  }
#pragma unroll
  for (int j = 0; j < 4; ++j) {
    int col = n0 + j * 16 + m;
    float g0 = gamma[col], b0 = beta[col];
    float g1 = gamma[CC + col], b1 = beta[CC + col];
    int p = col >> 6;
    int sub = ((col >> 3) & 3) * 16 + ((col >> 5) & 1) * 8 + (col & 7);
#pragma unroll
    for (int i = 0; i < 4; ++i)
#pragma unroll
      for (int r = 0; r < 4; ++r) {
        int row = m0 + i * 16 + g4 * 4 + r;
        int bb = row >> 11, jj = row & 2047;
        size_t addr = (((size_t)bb * 128 + (jj >> 4)) * 4 + p) * 1024 + (jj & 15) * 64 + sub;
        float z = acc[i][j][r];
        qout[addr] = f2fp8(z * g0 + b0);
        kout[addr] = f2fp8(z * g1 + b1);
      }
  }
}

// ---- fused attention v6: zero-LDS register flash ----
// 8 waves x 16 i-rows each (i-tile 128); per j-tile(64): each wave computes
// full-j S^T via swapped QK (K frags from global blocked layout), packs P to
// fp8 in-register, redistributes via ds_bpermute (intra-wave), then PV with
// V frags from global blocked layout. No LDS, no barriers.
__global__ __launch_bounds__(512, 2) void attn_kernel(
    const unsigned char* __restrict__ qB, const unsigned char* __restrict__ kB,
    const unsigned char* __restrict__ vB, const unsigned short* __restrict__ gg,
    unsigned short* __restrict__ og) {
  const int tid = threadIdx.x;
  const int wave = tid >> 6, lane = tid & 63;
  const int m = lane & 15, g4 = lane >> 4;
  const int id = blockIdx.x;
  const int b = id & 15, bx = id >> 4;   // 16 blocks per batch spread across XCDs
  const int i0 = bx * 128;
  const unsigned char* qp = qB + (size_t)(b * 128 + bx * 8 + wave) * 4096 + m * 64 + g4 * 16;
  const unsigned char* kp = kB + (size_t)b * 524288 + m * 64 + g4 * 16;
  const unsigned char* vp = vB + (size_t)b * 524288 + m * 64 + g4 * 16;

  uint4 qf[4];
#pragma unroll
  for (int p = 0; p < 4; ++p) qf[p] = *(const uint4*)(qp + p * 1024);
  uint4 kf[16], vf[16];
#pragma unroll
  for (int u = 0; u < 16; ++u) kf[u] = *(const uint4*)(kp + u * 1024);
#pragma unroll
  for (int u = 0; u < 16; ++u) vf[u] = *(const uint4*)(vp + u * 1024);

  floatx4 acc[16] = {};
  const int alo = (m + ((g4 & 1) << 5)) << 2;  // byte index of low-half src lane
  const int ahi = alo + 64;                    // +16 lanes

  for (int t = 0; t < NTILES; ++t) {
    // ---- QK: S^T[j=0..63][i = i0+wave*16+m] ----
    floatx4 sacc[4] = {};
#pragma unroll
    for (int jf = 0; jf < 4; ++jf)
#pragma unroll
      for (int p = 0; p < 4; ++p) {
        sacc[jf] = __builtin_amdgcn_mfma_f32_16x16x32_fp8_fp8(
            lo64(kf[jf * 4 + p]), lo64(qf[p]), sacc[jf], 0, 0, 0);
        sacc[jf] = __builtin_amdgcn_mfma_f32_16x16x32_fp8_fp8(
            hi64(kf[jf * 4 + p]), hi64(qf[p]), sacc[jf], 0, 0, 0);
      }
    // issue next K tile (kf regs now free; land during exchange+PV)
    if (t + 1 < NTILES) {
      const unsigned char* kn = kp + (size_t)(t + 1) * 16384;
#pragma unroll
      for (int u = 0; u < 16; ++u) kf[u] = *(const uint4*)(kn + u * 1024);
    }
    // ---- P' = (relu(S)/16)^2 -> fp8, packed per jf (byte r = j = jf*16+g4*4+r) ----
    unsigned pk[4];
#pragma unroll
    for (int jf = 0; jf < 4; ++jf) {
      float p0 = fmaxf(sacc[jf][0], 0.0f) * 0.0625f;
      float p1 = fmaxf(sacc[jf][1], 0.0f) * 0.0625f;
      float p2 = fmaxf(sacc[jf][2], 0.0f) * 0.0625f;
      float p3 = fmaxf(sacc[jf][3], 0.0f) * 0.0625f;
      unsigned u = __builtin_amdgcn_cvt_pk_fp8_f32(p2 * p2, p3 * p3, 0, true);
      pk[jf] = __builtin_amdgcn_cvt_pk_fp8_f32(p0 * p0, p1 * p1, (int)u, false);
    }
    // ---- intra-wave redistribution: ap[kk] = P'[i=m][j = kk*32 + g4*8 .. +7] ----
    long ap[2];
#pragma unroll
    for (int kk = 0; kk < 2; ++kk) {
      int A0 = __builtin_amdgcn_ds_bpermute(alo, (int)pk[2 * kk]);
      int B0 = __builtin_amdgcn_ds_bpermute(alo, (int)pk[2 * kk + 1]);
      int C0 = __builtin_amdgcn_ds_bpermute(ahi, (int)pk[2 * kk]);
      int D0 = __builtin_amdgcn_ds_bpermute(ahi, (int)pk[2 * kk + 1]);
      unsigned lo = (g4 & 2) ? (unsigned)B0 : (unsigned)A0;
      unsigned hi = (g4 & 2) ? (unsigned)D0 : (unsigned)C0;
      ap[kk] = (long)(((unsigned long long)hi << 32) | lo);
    }
    // ---- PV: O[i-block][c 0..255] ----
#pragma unroll
    for (int cf = 0; cf < 16; ++cf) {
      acc[cf] = __builtin_amdgcn_mfma_f32_16x16x32_fp8_fp8(ap[0], lo64(vf[cf]), acc[cf], 0, 0, 0);
      acc[cf] = __builtin_amdgcn_mfma_f32_16x16x32_fp8_fp8(ap[1], hi64(vf[cf]), acc[cf], 0, 0, 0);
    }
    // issue next V tile (vf regs now free; land during next QK)
    if (t + 1 < NTILES) {
      const unsigned char* vn = vp + (size_t)(t + 1) * 16384;
#pragma unroll
      for (int u = 0; u < 16; ++u) vf[u] = *(const uint4*)(vn + u * 1024);
    }
  }
  // ---- epilogue: scale 2^-14, gate, bf16 store ----
  const float sc = 1.0f / 16384.0f;
  const size_t bo = (size_t)b * NN * CC;
#pragma unroll
  for (int cf = 0; cf < 16; ++cf)
#pragma unroll
    for (int r = 0; r < 4; ++r) {
      int row = i0 + wave * 16 + g4 * 4 + r;
      int col = cf * 16 + m;
      size_t off = bo + (size_t)row * CC + col;
      og[off] = f2bf(acc[cf][r] * sc * bf2f(gg[off]));
    }
}

// --------- GEMM5: (V*gate) @ w_proj + b_proj + x -> fp32 out ---------
__global__ __launch_bounds__(256) void gemm_proj(
    const unsigned short* __restrict__ A, const unsigned short* __restrict__ BT,
    const float* __restrict__ bias, const float* __restrict__ xres,
    float* __restrict__ out) {
  int wave = threadIdx.x >> 6, lane = threadIdx.x & 63;
  int m = lane & 15, g4 = lane >> 4, kb = g4 * 8;
  int m0 = blockIdx.x * 128 + (wave & 1) * 64;
  int n0 = blockIdx.y * 128 + (wave >> 1) * 64;
  floatx4 acc[4][4] = {};
#pragma unroll
  for (int ks = 0; ks < 8; ++ks) {
    short8 af[4], bf[4];
#pragma unroll
    for (int i = 0; i < 4; ++i)
      af[i] = *(const short8*)(A + (size_t)(m0 + i * 16 + m) * CC + ks * 32 + kb);
#pragma unroll
    for (int j = 0; j < 4; ++j)
      bf[j] = *(const short8*)(BT + (size_t)(n0 + j * 16 + m) * CC + ks * 32 + kb);
#pragma unroll
    for (int i = 0; i < 4; ++i)
#pragma unroll
      for (int j = 0; j < 4; ++j)
        acc[i][j] = __builtin_amdgcn_mfma_f32_16x16x32_bf16(af[i], bf[j], acc[i][j], 0, 0, 0);
  }
#pragma unroll
  for (int j = 0; j < 4; ++j) {
    int col = n0 + j * 16 + m;
    float bv = bias[col];
#pragma unroll
    for (int i = 0; i < 4; ++i)
#pragma unroll
      for (int r = 0; r < 4; ++r) {
        int row = m0 + i * 16 + g4 * 4 + r;
        size_t rr = (size_t)row * CC;
        out[rr + col] = acc[i][j][r] + bv + xres[rr + col];
      }
  }
}

extern "C" void kernel_launch(void* const* d_in, const int* in_sizes, int n_in,
                              void* d_out, int out_size, void* d_ws, size_t ws_size,
                              hipStream_t stream) {
  const float* x        = (const float*)d_in[0];
  const float* ln_w     = (const float*)d_in[3];
  const float* ln_b     = (const float*)d_in[4];
  const float* w_hidden = (const float*)d_in[5];
  const float* b_hidden = (const float*)d_in[6];
  const float* w_kv     = (const float*)d_in[7];
  const float* gamma    = (const float*)d_in[8];
  const float* beta     = (const float*)d_in[9];
  const float* w_proj   = (const float*)d_in[10];
  const float* b_proj   = (const float*)d_in[11];
  float* out = (float*)d_out;
  char* ws = (char*)d_ws;

  const size_t SZ = (size_t)BN * CC * 2;  // one bf16 (BN x C) buffer (bytes)
  const size_t HZ = SZ / 2;               // one fp8 buffer
  unsigned short* slot0 = (unsigned short*)(ws);            // normed; later attn out
  unsigned short* gbuf  = (unsigned short*)(ws + SZ);
  unsigned char*  qB    = (unsigned char*)(ws + 2 * SZ);
  unsigned char*  kB    = (unsigned char*)(ws + 2 * SZ + HZ);
  unsigned char*  vB    = (unsigned char*)(ws + 2 * SZ + 2 * HZ);
  unsigned short* wTh   = (unsigned short*)(ws + 2 * SZ + 3 * HZ);
  unsigned short* wTkv  = (unsigned short*)(ws + 2 * SZ + 3 * HZ + 512 * 256 * 2);
  unsigned short* wTp   = (unsigned short*)(ws + 2 * SZ + 3 * HZ + 512 * 256 * 2 + 256 * 256 * 2);

  wconv_kernel<<<512, 256, 0, stream>>>(w_hidden, wTh, 256, 512);
  wconv_kernel<<<256, 256, 0, stream>>>(w_kv, wTkv, 256, 256);
  wconv_kernel<<<256, 256, 0, stream>>>(w_proj, wTp, 256, 256);
  ln_kernel<<<BN / 4, 256, 0, stream>>>(x, ln_w, ln_b, slot0);
  gemm_hidden<<<dim3(BN / 128, 4), 256, 0, stream>>>(slot0, wTh, b_hidden, vB, gbuf);
  gemm_kv<<<dim3(BN / 128, 2), 256, 0, stream>>>(slot0, wTkv, gamma, beta, qB, kB);
  // attn reads qB,kB,vB,gate; writes V*gate (bf16) into slot0 (normed dead)
  attn_kernel<<<256, 512, 0, stream>>>(qB, kB, vB, gbuf, slot0);
  gemm_proj<<<dim3(BN / 128, 2), 256, 0, stream>>>(slot0, wTp, b_proj, x, out);
}

// Round 6
// 178.463 us; speedup vs baseline: 1.3287x; 1.3287x over previous
//
#include <hip/hip_runtime.h>

#define BN 32768
#define NB 16
#define NN 2048
#define CC 256
#define JT 64
#define NTILES (NN / JT)

using short8  = __attribute__((ext_vector_type(8))) short;
using floatx4 = __attribute__((ext_vector_type(4))) float;

__device__ __forceinline__ unsigned short f2bf(float f) {
  unsigned u = __builtin_bit_cast(unsigned, f);
  u += 0x7fffu + ((u >> 16) & 1u);
  return (unsigned short)(u >> 16);
}
__device__ __forceinline__ float bf2f(unsigned short h) {
  unsigned u = ((unsigned)h) << 16;
  return __builtin_bit_cast(float, u);
}
__device__ __forceinline__ unsigned char f2fp8(float f) {
  return (unsigned char)(__builtin_amdgcn_cvt_pk_fp8_f32(f, f, 0, false) & 0xff);
}
__device__ __forceinline__ long lo64(uint4 v) {
  uint2 t; t.x = v.x; t.y = v.y; return __builtin_bit_cast(long, t);
}
__device__ __forceinline__ long hi64(uint4 v) {
  uint2 t; t.x = v.z; t.y = v.w; return __builtin_bit_cast(long, t);
}
__device__ __forceinline__ void gll16(const void* g, void* l) {
  __builtin_amdgcn_global_load_lds(
      (const __attribute__((address_space(1))) void*)g,
      (__attribute__((address_space(3))) void*)l, 16, 0, 0);
}

// ---------------- LayerNorm: one wave per row, bf16 output ----------------
__global__ __launch_bounds__(256) void ln_kernel(
    const float* __restrict__ x, const float* __restrict__ lw,
    const float* __restrict__ lb, unsigned short* __restrict__ normed) {
  int row  = blockIdx.x * 4 + (threadIdx.x >> 6);
  int lane = threadIdx.x & 63;
  float4 v = ((const float4*)(x + (size_t)row * CC))[lane];
  float s  = v.x + v.y + v.z + v.w;
  float s2 = v.x * v.x + v.y * v.y + v.z * v.z + v.w * v.w;
#pragma unroll
  for (int off = 32; off; off >>= 1) {
    s  += __shfl_xor(s, off);
    s2 += __shfl_xor(s2, off);
  }
  float mu = s * (1.0f / CC);
  float rs = rsqrtf(s2 * (1.0f / CC) - mu * mu + 1e-5f);
  float4 w = ((const float4*)lw)[lane];
  float4 b = ((const float4*)lb)[lane];
  ushort4 o;
  o.x = f2bf((v.x - mu) * rs * w.x + b.x);
  o.y = f2bf((v.y - mu) * rs * w.y + b.y);
  o.z = f2bf((v.z - mu) * rs * w.z + b.z);
  o.w = f2bf((v.w - mu) * rs * w.w + b.w);
  ((ushort4*)(normed + (size_t)row * CC))[lane] = o;
}

// --- all three weight transposes (fp32 KxN -> bf16 NxK) in one kernel ---
__global__ void wconv_kernel(const float* __restrict__ wh,
                             const float* __restrict__ wkv,
                             const float* __restrict__ wp,
                             unsigned short* __restrict__ wTh,
                             unsigned short* __restrict__ wTkv,
                             unsigned short* __restrict__ wTp) {
  int idx = blockIdx.x * 256 + threadIdx.x;
  if (idx < 131072) {            // 512x256
    int n = idx >> 8, k = idx & 255;
    wTh[idx] = f2bf(wh[(size_t)k * 512 + n]);
  } else if (idx < 196608) {     // 256x256
    int i2 = idx - 131072;
    int n = i2 >> 8, k = i2 & 255;
    wTkv[i2] = f2bf(wkv[(size_t)k * 256 + n]);
  } else {
    int i2 = idx - 196608;
    int n = i2 >> 8, k = i2 & 255;
    wTp[i2] = f2bf(wp[(size_t)k * 256 + n]);
  }
}

// --------- GEMM1: normed @ w_hidden + b, silu; v -> fp8 V tile-image, gate bf16 ---------
// V image: [b][jt=n>>6 (32)][c (256)][64B], 64B(jj=n&63) at g4a*16 + h*8 + jp
//   g4a=(jj>>3)&3, h=(jj>>5)&1, jp=jj&7   (16B slot g4a = {j=8g4a+0..7} ∪ {j=32+8g4a+0..7})
__global__ __launch_bounds__(256) void gemm_hidden(
    const unsigned short* __restrict__ A, const unsigned short* __restrict__ BT,
    const float* __restrict__ bias,
    unsigned char* __restrict__ vB, unsigned short* __restrict__ gout) {
  int wave = threadIdx.x >> 6, lane = threadIdx.x & 63;
  int m = lane & 15, g4 = lane >> 4, kb = g4 * 8;
  int m0 = blockIdx.x * 128 + (wave & 1) * 64;
  int n0 = blockIdx.y * 128 + (wave >> 1) * 64;
  floatx4 acc[4][4] = {};
#pragma unroll
  for (int ks = 0; ks < 8; ++ks) {
    short8 af[4], bf[4];
#pragma unroll
    for (int i = 0; i < 4; ++i)
      af[i] = *(const short8*)(A + (size_t)(m0 + i * 16 + m) * CC + ks * 32 + kb);
#pragma unroll
    for (int j = 0; j < 4; ++j)
      bf[j] = *(const short8*)(BT + (size_t)(n0 + j * 16 + m) * CC + ks * 32 + kb);
#pragma unroll
    for (int i = 0; i < 4; ++i)
#pragma unroll
      for (int j = 0; j < 4; ++j)
        acc[i][j] = __builtin_amdgcn_mfma_f32_16x16x32_bf16(af[i], bf[j], acc[i][j], 0, 0, 0);
  }
  // hoisted image bases
  const size_t tb = ((size_t)(m0 >> 11) * 32 + ((m0 & 2047) >> 6)) * 16384;
#pragma unroll
  for (int j = 0; j < 4; ++j) {
    int col = n0 + j * 16 + m;
    float bv = bias[col];
    size_t colb = tb + (size_t)col * 64;   // valid when col<256
#pragma unroll
    for (int i = 0; i < 4; ++i) {
      int h8 = ((i >> 1) & 1) * 8;
      int i2 = i * 2;
#pragma unroll
      for (int r = 0; r < 4; ++r) {
        int row = m0 + i * 16 + g4 * 4 + r;
        float hh = acc[i][j][r] + bv;
        float sv = hh / (1.0f + __expf(-hh));
        if (col < CC) {
          int val = g4 * 4 + r;
          int g4a = (i2 + (val >> 3)) & 3;
          vB[colb + g4a * 16 + h8 + (val & 7)] = f2fp8(sv);
        } else {
          gout[(size_t)row * CC + col - CC] = f2bf(sv);
        }
      }
    }
  }
}

// ----------- GEMM2: normed @ w_kv -> Z; q,k fp8 in tile-image layout -----------
// image: [b][jblk=n>>4 (128)][ks2=c>>6][ (n&15)*64 + ((c>>3)&3)*16 + ((c>>5)&1)*8 + (c&7) ]
__global__ __launch_bounds__(256) void gemm_kv(
    const unsigned short* __restrict__ A, const unsigned short* __restrict__ BT,
    const float* __restrict__ gamma, const float* __restrict__ beta,
    unsigned char* __restrict__ qout, unsigned char* __restrict__ kout) {
  int wave = threadIdx.x >> 6, lane = threadIdx.x & 63;
  int m = lane & 15, g4 = lane >> 4, kb = g4 * 8;
  int m0 = blockIdx.x * 128 + (wave & 1) * 64;
  int n0 = blockIdx.y * 128 + (wave >> 1) * 64;
  floatx4 acc[4][4] = {};
#pragma unroll
  for (int ks = 0; ks < 8; ++ks) {
    short8 af[4], bf[4];
#pragma unroll
    for (int i = 0; i < 4; ++i)
      af[i] = *(const short8*)(A + (size_t)(m0 + i * 16 + m) * CC + ks * 32 + kb);
#pragma unroll
    for (int j = 0; j < 4; ++j)
      bf[j] = *(const short8*)(BT + (size_t)(n0 + j * 16 + m) * CC + ks * 32 + kb);
#pragma unroll
    for (int i = 0; i < 4; ++i)
#pragma unroll
      for (int j = 0; j < 4; ++j)
        acc[i][j] = __builtin_amdgcn_mfma_f32_16x16x32_bf16(af[i], bf[j], acc[i][j], 0, 0, 0);
  }
  const size_t base0 = ((size_t)(m0 >> 11) * 128 + ((m0 & 2047) >> 4)) * 4096;
  const int mm = g4 * 4;
#pragma unroll
  for (int j = 0; j < 4; ++j) {
    int col = n0 + j * 16 + m;
    float g0 = gamma[col], b0 = beta[col];
    float g1 = gamma[CC + col], b1 = beta[CC + col];
    int cbase = (col >> 6) * 1024 + ((col >> 3) & 3) * 16 + ((col >> 5) & 1) * 8 + (col & 7);
#pragma unroll
    for (int i = 0; i < 4; ++i) {
      size_t ibase = base0 + (size_t)i * 4096 + cbase;
#pragma unroll
      for (int r = 0; r < 4; ++r) {
        float z = acc[i][j][r];
        size_t addr = ibase + (size_t)(mm + r) * 64;
        qout[addr] = f2fp8(z * g0 + b0);
        kout[addr] = f2fp8(z * g1 + b1);
      }
    }
  }
}

// ---- fused attention v7: tile-image DMA staging + intra-wave bpermute P ----
// 4 waves, i-tile 64 (wave owns one 16-i block), j-tile 64, dbuf LDS, 1 barrier/tile.
__global__ __launch_bounds__(256, 2) void attn_kernel(
    const unsigned char* __restrict__ qB, const unsigned char* __restrict__ kB,
    const unsigned char* __restrict__ vB, const unsigned short* __restrict__ gg,
    unsigned short* __restrict__ og) {
  __shared__ unsigned char Kl[2][16384];
  __shared__ unsigned char Vl[2][16384];
  const int tid = threadIdx.x;
  const int wave = tid >> 6, lane = tid & 63;
  const int m = lane & 15, g4 = lane >> 4;
  const int id = blockIdx.x;
  const int b = id & 15, bx = id >> 4;   // batch b -> XCD b%8 (32 blocks/batch co-located)
  const int i0 = bx * 64;
  const unsigned char* kimg = kB + (size_t)b * 524288;
  const unsigned char* vimg = vB + (size_t)b * 524288;

  // Q fragments for this wave's 16-i block (from q tile-image)
  const int iblk = bx * 4 + wave;
  uint4 qf[4];
#pragma unroll
  for (int ks2 = 0; ks2 < 4; ++ks2)
    qf[ks2] = *(const uint4*)(qB + ((size_t)(b * 128 + iblk) * 4 + ks2) * 1024 + m * 64 + g4 * 16);

  floatx4 acc[16] = {};
  const int alo = (m + ((g4 & 1) << 5)) << 2;
  const int ahi = alo + 64;

  auto stage = [&](int buf, int t) {
    const unsigned char* kt = kimg + (size_t)t * 16384;
    const unsigned char* vt = vimg + (size_t)t * 16384;
#pragma unroll
    for (int it = 0; it < 4; ++it) {
      int o = (it * 256 + tid) * 16;
      gll16(kt + o, &Kl[buf][o]);
      gll16(vt + o, &Vl[buf][o]);
    }
  };

  stage(0, 0);
  for (int t = 0; t < NTILES; ++t) {
    const int cur = t & 1;
    __syncthreads();  // drains this tile's DMA (implicit vmcnt(0)); prior reads done
    if (t + 1 < NTILES) stage(cur ^ 1, t + 1);
    // ---- QK: S^T[j 0..63][i=m of this wave's block] ----
    floatx4 sacc[4] = {};
#pragma unroll
    for (int ks2 = 0; ks2 < 4; ++ks2) {
#pragma unroll
      for (int jf = 0; jf < 4; ++jf) {
        uint4 kf = *(const uint4*)(&Kl[cur][(jf * 4 + ks2) * 1024 + m * 64 + g4 * 16]);
        sacc[jf] = __builtin_amdgcn_mfma_f32_16x16x32_fp8_fp8(
            lo64(kf), lo64(qf[ks2]), sacc[jf], 0, 0, 0);
        sacc[jf] = __builtin_amdgcn_mfma_f32_16x16x32_fp8_fp8(
            hi64(kf), hi64(qf[ks2]), sacc[jf], 0, 0, 0);
      }
    }
    // ---- P' = (relu(S)/16)^2 -> fp8 packed (byte r = j = jf*16+g4*4+r) ----
    unsigned pk[4];
#pragma unroll
    for (int jf = 0; jf < 4; ++jf) {
      float p0 = fmaxf(sacc[jf][0], 0.0f) * 0.0625f;
      float p1 = fmaxf(sacc[jf][1], 0.0f) * 0.0625f;
      float p2 = fmaxf(sacc[jf][2], 0.0f) * 0.0625f;
      float p3 = fmaxf(sacc[jf][3], 0.0f) * 0.0625f;
      unsigned u = __builtin_amdgcn_cvt_pk_fp8_f32(p2 * p2, p3 * p3, 0, true);
      pk[jf] = __builtin_amdgcn_cvt_pk_fp8_f32(p0 * p0, p1 * p1, (int)u, false);
    }
    // ---- intra-wave exchange: ap[kk] = P'[i=m][j = kk*32 + g4*8 .. +7] ----
    long ap[2];
#pragma unroll
    for (int kk = 0; kk < 2; ++kk) {
      int A0 = __builtin_amdgcn_ds_bpermute(alo, (int)pk[2 * kk]);
      int B0 = __builtin_amdgcn_ds_bpermute(alo, (int)pk[2 * kk + 1]);
      int C0 = __builtin_amdgcn_ds_bpermute(ahi, (int)pk[2 * kk]);
      int D0 = __builtin_amdgcn_ds_bpermute(ahi, (int)pk[2 * kk + 1]);
      unsigned lo = (g4 & 2) ? (unsigned)B0 : (unsigned)A0;
      unsigned hi = (g4 & 2) ? (unsigned)D0 : (unsigned)C0;
      ap[kk] = (long)(((unsigned long long)hi << 32) | lo);
    }
    // ---- PV: O[i-block][c 0..255] ----
#pragma unroll
    for (int cf = 0; cf < 16; ++cf) {
      uint4 vfr = *(const uint4*)(&Vl[cur][cf * 1024 + m * 64 + g4 * 16]);
      acc[cf] = __builtin_amdgcn_mfma_f32_16x16x32_fp8_fp8(ap[0], lo64(vfr), acc[cf], 0, 0, 0);
      acc[cf] = __builtin_amdgcn_mfma_f32_16x16x32_fp8_fp8(ap[1], hi64(vfr), acc[cf], 0, 0, 0);
    }
  }
  // ---- epilogue: scale 2^-14, gate, bf16 store ----
  const float sc = 1.0f / 16384.0f;
  const size_t bo = (size_t)b * NN * CC;
#pragma unroll
  for (int cf = 0; cf < 16; ++cf)
#pragma unroll
    for (int r = 0; r < 4; ++r) {
      int row = i0 + wave * 16 + g4 * 4 + r;
      int col = cf * 16 + m;
      size_t off = bo + (size_t)row * CC + col;
      og[off] = f2bf(acc[cf][r] * sc * bf2f(gg[off]));
    }
}

// --------- GEMM5: (V*gate) @ w_proj + b_proj + x -> fp32 out ---------
__global__ __launch_bounds__(256) void gemm_proj(
    const unsigned short* __restrict__ A, const unsigned short* __restrict__ BT,
    const float* __restrict__ bias, const float* __restrict__ xres,
    float* __restrict__ out) {
  int wave = threadIdx.x >> 6, lane = threadIdx.x & 63;
  int m = lane & 15, g4 = lane >> 4, kb = g4 * 8;
  int m0 = blockIdx.x * 128 + (wave & 1) * 64;
  int n0 = blockIdx.y * 128 + (wave >> 1) * 64;
  floatx4 acc[4][4] = {};
#pragma unroll
  for (int ks = 0; ks < 8; ++ks) {
    short8 af[4], bf[4];
#pragma unroll
    for (int i = 0; i < 4; ++i)
      af[i] = *(const short8*)(A + (size_t)(m0 + i * 16 + m) * CC + ks * 32 + kb);
#pragma unroll
    for (int j = 0; j < 4; ++j)
      bf[j] = *(const short8*)(BT + (size_t)(n0 + j * 16 + m) * CC + ks * 32 + kb);
#pragma unroll
    for (int i = 0; i < 4; ++i)
#pragma unroll
      for (int j = 0; j < 4; ++j)
        acc[i][j] = __builtin_amdgcn_mfma_f32_16x16x32_bf16(af[i], bf[j], acc[i][j], 0, 0, 0);
  }
#pragma unroll
  for (int j = 0; j < 4; ++j) {
    int col = n0 + j * 16 + m;
    float bv = bias[col];
#pragma unroll
    for (int i = 0; i < 4; ++i)
#pragma unroll
      for (int r = 0; r < 4; ++r) {
        int row = m0 + i * 16 + g4 * 4 + r;
        size_t rr = (size_t)row * CC;
        out[rr + col] = acc[i][j][r] + bv + xres[rr + col];
      }
  }
}

extern "C" void kernel_launch(void* const* d_in, const int* in_sizes, int n_in,
                              void* d_out, int out_size, void* d_ws, size_t ws_size,
                              hipStream_t stream) {
  const float* x        = (const float*)d_in[0];
  const float* ln_w     = (const float*)d_in[3];
  const float* ln_b     = (const float*)d_in[4];
  const float* w_hidden = (const float*)d_in[5];
  const float* b_hidden = (const float*)d_in[6];
  const float* w_kv     = (const float*)d_in[7];
  const float* gamma    = (const float*)d_in[8];
  const float* beta     = (const float*)d_in[9];
  const float* w_proj   = (const float*)d_in[10];
  const float* b_proj   = (const float*)d_in[11];
  float* out = (float*)d_out;
  char* ws = (char*)d_ws;

  const size_t SZ = (size_t)BN * CC * 2;  // one bf16 (BN x C) buffer (bytes)
  const size_t HZ = SZ / 2;               // one fp8 buffer
  unsigned short* slot0 = (unsigned short*)(ws);            // normed; later attn out
  unsigned short* gbuf  = (unsigned short*)(ws + SZ);
  unsigned char*  qB    = (unsigned char*)(ws + 2 * SZ);
  unsigned char*  kB    = (unsigned char*)(ws + 2 * SZ + HZ);
  unsigned char*  vB    = (unsigned char*)(ws + 2 * SZ + 2 * HZ);
  unsigned short* wTh   = (unsigned short*)(ws + 2 * SZ + 3 * HZ);
  unsigned short* wTkv  = (unsigned short*)(ws + 2 * SZ + 3 * HZ + 512 * 256 * 2);
  unsigned short* wTp   = (unsigned short*)(ws + 2 * SZ + 3 * HZ + 512 * 256 * 2 + 256 * 256 * 2);

  wconv_kernel<<<1024, 256, 0, stream>>>(w_hidden, w_kv, w_proj, wTh, wTkv, wTp);
  ln_kernel<<<BN / 4, 256, 0, stream>>>(x, ln_w, ln_b, slot0);
  gemm_hidden<<<dim3(BN / 128, 4), 256, 0, stream>>>(slot0, wTh, b_hidden, vB, gbuf);
  gemm_kv<<<dim3(BN / 128, 2), 256, 0, stream>>>(slot0, wTkv, gamma, beta, qB, kB);
  // attn reads qB,kB,vB,gate; writes V*gate (bf16) into slot0 (normed dead)
  attn_kernel<<<512, 256, 0, stream>>>(qB, kB, vB, gbuf, slot0);
  gemm_proj<<<dim3(BN / 128, 2), 256, 0, stream>>>(slot0, wTp, b_proj, x, out);
}